// Round 1
// baseline (445.122 us; speedup 1.0000x reference)
//
#include <hip/hip_runtime.h>

// Problem geometry (fixed by the reference): [B=2, D=160, H=192, W=160, C=3]
constexpr int D_ = 160;
constexpr int H_ = 192;
constexpr int W_ = 160;
constexpr int NVOX = D_ * H_ * W_;   // per-batch voxel count = 4,915,200
constexpr int BATCH = 2;

// out = trilinear(d1, grid + d2) + d2, with neurite-style clipping:
//   loc0c = clip(floor(loc), 0, dim-1)
//   loc1c = clip(floor(loc)+1, 0, dim-1)
//   w_floor = clip(loc1c - loc, 0, 1); w_ceil = 1 - w_floor
__global__ __launch_bounds__(256) void compose_kernel(
    const float* __restrict__ d1,
    const float* __restrict__ d2,
    float* __restrict__ out)
{
    int idx = blockIdx.x * 256 + threadIdx.x;
    if (idx >= BATCH * NVOX) return;

    int b = idx / NVOX;
    int v = idx - b * NVOX;
    int z = v % W_;
    int t = v / W_;
    int y = t % H_;
    int x = t / H_;

    const float* __restrict__ d1b = d1 + (size_t)b * NVOX * 3;

    const size_t o3 = (size_t)idx * 3;
    const float dxv = d2[o3 + 0];
    const float dyv = d2[o3 + 1];
    const float dzv = d2[o3 + 2];

    const float lx = (float)x + dxv;
    const float ly = (float)y + dyv;
    const float lz = (float)z + dzv;

    // X axis
    float fx  = floorf(lx);
    float x0f = fminf(fmaxf(fx,        0.f), (float)(D_ - 1));
    float x1f = fminf(fmaxf(fx + 1.f,  0.f), (float)(D_ - 1));
    float wx0 = fminf(fmaxf(x1f - lx,  0.f), 1.f);
    float wx1 = 1.f - wx0;
    int ix0 = (int)x0f, ix1 = (int)x1f;

    // Y axis
    float fy  = floorf(ly);
    float y0f = fminf(fmaxf(fy,        0.f), (float)(H_ - 1));
    float y1f = fminf(fmaxf(fy + 1.f,  0.f), (float)(H_ - 1));
    float wy0 = fminf(fmaxf(y1f - ly,  0.f), 1.f);
    float wy1 = 1.f - wy0;
    int iy0 = (int)y0f, iy1 = (int)y1f;

    // Z axis
    float fz  = floorf(lz);
    float z0f = fminf(fmaxf(fz,        0.f), (float)(W_ - 1));
    float z1f = fminf(fmaxf(fz + 1.f,  0.f), (float)(W_ - 1));
    float wz0 = fminf(fmaxf(z1f - lz,  0.f), 1.f);
    float wz1 = 1.f - wz0;
    int iz0 = (int)z0f, iz1 = (int)z1f;

    // Row bases for the 4 (x,y) combos
    int b00 = (ix0 * H_ + iy0) * W_;
    int b01 = (ix0 * H_ + iy1) * W_;
    int b10 = (ix1 * H_ + iy0) * W_;
    int b11 = (ix1 * H_ + iy1) * W_;

    float wxy00 = wx0 * wy0;
    float wxy01 = wx0 * wy1;
    float wxy10 = wx1 * wy0;
    float wxy11 = wx1 * wy1;

    float acc0 = 0.f, acc1 = 0.f, acc2 = 0.f;

    // Corner order matches the reference's itertools.product((0,1),repeat=3)
    // (x-major: 000,001,010,011,100,101,110,111) for closest float summation.
    #define GATHER(VOX, WGT)                                   \
        do {                                                   \
            const float* __restrict__ p = d1b + (size_t)(VOX) * 3; \
            float w = (WGT);                                   \
            acc0 = fmaf(w, p[0], acc0);                        \
            acc1 = fmaf(w, p[1], acc1);                        \
            acc2 = fmaf(w, p[2], acc2);                        \
        } while (0)

    GATHER(b00 + iz0, wxy00 * wz0);
    GATHER(b00 + iz1, wxy00 * wz1);
    GATHER(b01 + iz0, wxy01 * wz0);
    GATHER(b01 + iz1, wxy01 * wz1);
    GATHER(b10 + iz0, wxy10 * wz0);
    GATHER(b10 + iz1, wxy10 * wz1);
    GATHER(b11 + iz0, wxy11 * wz0);
    GATHER(b11 + iz1, wxy11 * wz1);

    #undef GATHER

    out[o3 + 0] = acc0 + dxv;
    out[o3 + 1] = acc1 + dyv;
    out[o3 + 2] = acc2 + dzv;
}

extern "C" void kernel_launch(void* const* d_in, const int* in_sizes, int n_in,
                              void* d_out, int out_size, void* d_ws, size_t ws_size,
                              hipStream_t stream)
{
    const float* d1 = (const float*)d_in[0];  // disp_1
    const float* d2 = (const float*)d_in[1];  // disp_2
    float* out = (float*)d_out;

    const int total = BATCH * NVOX;           // 9,830,400 voxels
    const int blocks = (total + 255) / 256;   // 38,400 blocks

    compose_kernel<<<dim3(blocks), dim3(256), 0, stream>>>(d1, d2, out);
}